// Round 2
// baseline (27362.222 us; speedup 1.0000x reference)
//
#include <hip/hip_runtime.h>

typedef short bf16x8 __attribute__((ext_vector_type(8)));
typedef float f32x4 __attribute__((ext_vector_type(4)));

static __device__ __forceinline__ unsigned short f2bf(float f) {
    unsigned int u = __float_as_uint(f);
    unsigned int r = (u + 0x7fffu + ((u >> 16) & 1u)) >> 16;
    return (unsigned short)r;
}
static __device__ __forceinline__ float sigmoidf_(float x) {
    return 1.0f / (1.0f + __expf(-x));
}
static __device__ __forceinline__ float tanhf_(float x) {
    return 2.0f / (1.0f + __expf(-2.0f * x)) - 1.0f;
}

// ---- activation layout: element (k,b) at ((k>>2)*32 + b)*4 + (k&3)  (k4-interleaved) ----

// ---------------- grid barrier (device scope, sense via generation counter) ----------------
static __device__ __forceinline__ void gbar(unsigned* bar, int nb) {
    __syncthreads();
    if (threadIdx.x == 0) {
        unsigned g = __hip_atomic_load(bar + 32, __ATOMIC_RELAXED, __HIP_MEMORY_SCOPE_AGENT);
        unsigned a = __hip_atomic_fetch_add(bar, 1u, __ATOMIC_ACQ_REL, __HIP_MEMORY_SCOPE_AGENT);
        if (a == (unsigned)nb - 1u) {
            __hip_atomic_store(bar, 0u, __ATOMIC_RELAXED, __HIP_MEMORY_SCOPE_AGENT);
            __hip_atomic_store(bar + 32, g + 1u, __ATOMIC_RELEASE, __HIP_MEMORY_SCOPE_AGENT);
        } else {
            while (__hip_atomic_load(bar + 32, __ATOMIC_ACQUIRE, __HIP_MEMORY_SCOPE_AGENT) == g) {
                __builtin_amdgcn_s_sleep(1);
            }
        }
    }
    __syncthreads();
}

// ---------------- mog phase: one j-quad. dst = 2*sigmoid(gin@W^T + b) * src ----------------
static __device__ __forceinline__ void mog_phase(int g256, const float* __restrict__ gin,
                                                 const float* __restrict__ W,
                                                 const float* __restrict__ bias,
                                                 const float* __restrict__ src,
                                                 float* __restrict__ dst) {
    static __shared__ float red[4][4][32];
    int tid = threadIdx.x, b = tid & 31, kq = tid >> 5;
    int j0 = g256 * 4;
    const float* gp = gin + kq * 4096 + b * 4;             // k-slice [kq*128, +128)
    const float* w0 = W + (size_t)j0 * 1024 + kq * 128;
    float a0 = 0.f, a1 = 0.f, a2 = 0.f, a3 = 0.f;
#pragma unroll 4
    for (int c = 0; c < 32; ++c) {
        float4 a = *(const float4*)(gp + c * 128);
        float4 w = *(const float4*)(w0 + c * 4);
        a0 += a.x * w.x + a.y * w.y + a.z * w.z + a.w * w.w;
        w = *(const float4*)(w0 + 1024 + c * 4);
        a1 += a.x * w.x + a.y * w.y + a.z * w.z + a.w * w.w;
        w = *(const float4*)(w0 + 2048 + c * 4);
        a2 += a.x * w.x + a.y * w.y + a.z * w.z + a.w * w.w;
        w = *(const float4*)(w0 + 3072 + c * 4);
        a3 += a.x * w.x + a.y * w.y + a.z * w.z + a.w * w.w;
    }
    a0 += __shfl_xor(a0, 32);
    a1 += __shfl_xor(a1, 32);
    a2 += __shfl_xor(a2, 32);
    a3 += __shfl_xor(a3, 32);
    int wv = tid >> 6;
    if ((tid & 32) == 0) {
        red[wv][0][b] = a0; red[wv][1][b] = a1; red[wv][2][b] = a2; red[wv][3][b] = a3;
    }
    __syncthreads();
    if (tid < 128) {
        int j = tid >> 5, bb = tid & 31;
        float s = (red[0][j][bb] + red[1][j][bb]) + (red[2][j][bb] + red[3][j][bb]);
        int ja = j0 + j;
        s += bias[ja];
        float gmul = 2.0f * sigmoidf_(s);
        int idx = ((ja >> 2) * 32 + bb) * 4 + (ja & 3);
        dst[idx] = gmul * src[idx];
    }
}

// ---------------- lstm phase: one jj-quad across all 4 gates ----------------
static __device__ __forceinline__ void lstm_phase(int g256, const float* __restrict__ x,
                                                  const float* __restrict__ hm,
                                                  const float* __restrict__ Wih,
                                                  const float* __restrict__ Whh,
                                                  const float* __restrict__ bih,
                                                  const float* __restrict__ bhh,
                                                  float* __restrict__ c, float* __restrict__ h,
                                                  float* __restrict__ copyT,
                                                  float* __restrict__ hsOut, int t) {
    static __shared__ float red2[4][16][32];
    int tid = threadIdx.x, b = tid & 31, kq = tid >> 5;
    int jj0 = g256 * 4;
    const float* act = (kq < 4) ? x : hm;
    const float* Wb  = (kq < 4) ? Wih : Whh;
    int kbase = (kq & 3) * 256;                             // k-slice [kbase, +256) within side
    const float* ap = act + (kbase >> 2) * 128 + b * 4;
    const float* wbase = Wb + (size_t)jj0 * 1024 + kbase;
    float acc[16];
#pragma unroll
    for (int i = 0; i < 16; ++i) acc[i] = 0.f;
#pragma unroll 2
    for (int c0 = 0; c0 < 64; ++c0) {
        float4 a = *(const float4*)(ap + c0 * 128);
#pragma unroll
        for (int q = 0; q < 4; ++q) {
#pragma unroll
            for (int jj = 0; jj < 4; ++jj) {
                float4 w = *(const float4*)(wbase + (size_t)(q * 1024 + jj) * 1024 + c0 * 4);
                acc[q * 4 + jj] += a.x * w.x + a.y * w.y + a.z * w.z + a.w * w.w;
            }
        }
    }
#pragma unroll
    for (int i = 0; i < 16; ++i) acc[i] += __shfl_xor(acc[i], 32);
    int wv = tid >> 6;
    if ((tid & 32) == 0) {
#pragma unroll
        for (int i = 0; i < 16; ++i) red2[wv][i][b] = acc[i];
    }
    __syncthreads();
    if (tid < 128) {
        int jj = tid >> 5, bb = tid & 31;
        int ja = jj0 + jj;
        float gi = 0.f, gf = 0.f, gg = 0.f, go = 0.f;
#pragma unroll
        for (int w = 0; w < 4; ++w) {
            gi += red2[w][0 * 4 + jj][bb];
            gf += red2[w][1 * 4 + jj][bb];
            gg += red2[w][2 * 4 + jj][bb];
            go += red2[w][3 * 4 + jj][bb];
        }
        gi += bih[ja] + bhh[ja];
        gf += bih[1024 + ja] + bhh[1024 + ja];
        gg += bih[2048 + ja] + bhh[2048 + ja];
        go += bih[3072 + ja] + bhh[3072 + ja];
        int idx = ((ja >> 2) * 32 + bb) * 4 + (ja & 3);
        float cn = sigmoidf_(gf) * c[idx] + sigmoidf_(gi) * tanhf_(gg);
        c[idx] = cn;
        float hn = sigmoidf_(go) * tanhf_(cn);
        h[idx] = hn;
        if (copyT) copyT[idx] = hn;
        if (hsOut) hsOut[(size_t)bb * 65536 + (size_t)t * 1024 + ja] = hn;
    }
}

// ---------------- persistent recurrence kernel ----------------
struct RArgs {
    const float *m1W, *m1b, *Wih1, *Whh1, *bih1, *bhh1;
    const float *m2W, *m2b, *Wih2, *Whh2, *bih2, *bhh2;
    float *XT, *st, *hs;
    unsigned* bar;
};

__global__ __launch_bounds__(256, 2) void reck(RArgs A) {
    const int blk = blockIdx.x, NB = gridDim.x;
    float* h1  = A.st;
    float* c1  = A.st + 32768;
    float* h2  = A.st + 65536;
    float* c2  = A.st + 98304;
    float* hm1 = A.st + 131072;
    float* hm2 = A.st + 163840;
    float* x2v = A.st + 196608;                 // two buffers of 32768

    for (int s = 0; s <= 64; ++s) {
        const bool aA = (s < 64), aB = (s > 0);
        const int tA = s, tB = s - 1;
        float* xA = A.XT + (size_t)(aA ? tA : 0) * 32768;
        float* xB = x2v + (tB & 1 & (aB ? 1 : 0)) * 32768;

        for (int ph = 0; ph < 5; ++ph) {
            const float *gA, *sA, *gB, *sB;
            float *dA, *dB;
            switch (ph) {
                default:
                case 0: gA = h1;  sA = xA;  dA = xA;  gB = h2;  sB = xB;  dB = xB;  break;
                case 1: gA = xA;  sA = h1;  dA = hm1; gB = xB;  sB = h2;  dB = hm2; break;
                case 2: gA = hm1; sA = xA;  dA = xA;  gB = hm2; sB = xB;  dB = xB;  break;
                case 3: gA = xA;  sA = hm1; dA = hm1; gB = xB;  sB = hm2; dB = hm2; break;
                case 4: gA = hm1; sA = xA;  dA = xA;  gB = hm2; sB = xB;  dB = xB;  break;
            }
            for (int g = blk; g < 512; g += NB) {
                if (g < 256) {
                    if (aA) mog_phase(g, gA, A.m1W + ph * 1048576, A.m1b + ph * 1024, sA, dA);
                } else {
                    if (aB) mog_phase(g - 256, gB, A.m2W + ph * 1048576, A.m2b + ph * 1024, sB, dB);
                }
            }
            gbar(A.bar, NB);
        }
        for (int g = blk; g < 512; g += NB) {
            if (g < 256) {
                if (aA) lstm_phase(g, xA, hm1, A.Wih1, A.Whh1, A.bih1, A.bhh1,
                                   c1, h1, x2v + (tA & 1) * 32768, nullptr, 0);
            } else {
                if (aB) lstm_phase(g - 256, xB, hm2, A.Wih2, A.Whh2, A.bih2, A.bhh2,
                                   c2, h2, nullptr, A.hs, tB);
            }
        }
        gbar(A.bar, NB);
    }
}

// ---------------- embedding gather into k4-interleaved layout ----------------
__global__ __launch_bounds__(256) void gather_embed(const int* __restrict__ seq,
                                                    const float* __restrict__ emb,
                                                    float* __restrict__ XT) {
    int t = blockIdx.x;
    const float4* emb4 = (const float4*)emb;
    float4* xt4 = (float4*)(XT + (size_t)t * 32768);
#pragma unroll 4
    for (int b = 0; b < 32; ++b) {
        int row = seq[b * 64 + t];
        float4 v = emb4[(size_t)row * 256 + threadIdx.x];
        xt4[threadIdx.x * 32 + b] = v;
    }
}

// ---------------- fp32 -> bf16 ----------------
__global__ __launch_bounds__(256) void f32_to_bf16(const float* __restrict__ in,
                                                   unsigned short* __restrict__ out, int n) {
    int i = (blockIdx.x * 256 + threadIdx.x) * 8;
    if (i + 7 < n) {
        float4 f0 = *(const float4*)(in + i);
        float4 f1 = *(const float4*)(in + i + 4);
        bf16x8 v;
        v[0] = (short)f2bf(f0.x); v[1] = (short)f2bf(f0.y);
        v[2] = (short)f2bf(f0.z); v[3] = (short)f2bf(f0.w);
        v[4] = (short)f2bf(f1.x); v[5] = (short)f2bf(f1.y);
        v[6] = (short)f2bf(f1.z); v[7] = (short)f2bf(f1.w);
        *(bf16x8*)(out + i) = v;
    }
}

// ---------------- output projection (bf16 MFMA, 128x128 tile) ----------------
__global__ __launch_bounds__(256) void out_proj(const unsigned short* __restrict__ hsb,
                                                const float* __restrict__ emb,
                                                const float* __restrict__ fcb,
                                                float* __restrict__ out) {
    __shared__ unsigned short Al[128 * 40];
    __shared__ unsigned short Bl[128 * 40];
    int tid = threadIdx.x;
    int n0 = blockIdx.x * 128;
    int m0 = blockIdx.y * 128;
    int wid = tid >> 6, l = tid & 63;
    int wm = wid >> 1, wn = wid & 1;
    int c16 = l & 15, kg = l >> 4;

    f32x4 acc[4][4];
#pragma unroll
    for (int i = 0; i < 4; i++)
#pragma unroll
        for (int j = 0; j < 4; j++) acc[i][j] = (f32x4){0.f, 0.f, 0.f, 0.f};

    for (int k0 = 0; k0 < 1024; k0 += 32) {
#pragma unroll
        for (int i = 0; i < 2; i++) {
            int id = i * 256 + tid;
            int r = id >> 2, cc = id & 3;
            *(bf16x8*)&Al[r * 40 + cc * 8] =
                *(const bf16x8*)(hsb + (size_t)(m0 + r) * 1024 + k0 + cc * 8);
        }
#pragma unroll
        for (int i = 0; i < 2; i++) {
            int id = i * 256 + tid;
            int r = id >> 2, cc = id & 3;
            const float* src = emb + (size_t)(n0 + r) * 1024 + k0 + cc * 8;
            float4 f0 = *(const float4*)(src);
            float4 f1 = *(const float4*)(src + 4);
            bf16x8 v;
            v[0] = (short)f2bf(f0.x); v[1] = (short)f2bf(f0.y);
            v[2] = (short)f2bf(f0.z); v[3] = (short)f2bf(f0.w);
            v[4] = (short)f2bf(f1.x); v[5] = (short)f2bf(f1.y);
            v[6] = (short)f2bf(f1.z); v[7] = (short)f2bf(f1.w);
            *(bf16x8*)&Bl[r * 40 + cc * 8] = v;
        }
        __syncthreads();

        bf16x8 afr[4], bfr[4];
#pragma unroll
        for (int i = 0; i < 4; i++)
            afr[i] = *(const bf16x8*)&Al[(wm * 64 + i * 16 + c16) * 40 + kg * 8];
#pragma unroll
        for (int j = 0; j < 4; j++)
            bfr[j] = *(const bf16x8*)&Bl[(wn * 64 + j * 16 + c16) * 40 + kg * 8];
#pragma unroll
        for (int i = 0; i < 4; i++)
#pragma unroll
            for (int j = 0; j < 4; j++)
                acc[i][j] = __builtin_amdgcn_mfma_f32_16x16x32_bf16(afr[i], bfr[j], acc[i][j], 0, 0, 0);
        __syncthreads();
    }

#pragma unroll
    for (int i = 0; i < 4; i++) {
        int row = m0 + wm * 64 + i * 16 + kg * 4;
#pragma unroll
        for (int j = 0; j < 4; j++) {
            int col = n0 + wn * 64 + j * 16 + c16;
            float fb = fcb[col];
#pragma unroll
            for (int r = 0; r < 4; r++)
                out[(size_t)(row + r) * 32000 + col] = acc[i][j][r] + fb;
        }
    }
}

// ---------------- host ----------------
extern "C" void kernel_launch(void* const* d_in, const int* in_sizes, int n_in,
                              void* d_out, int out_size, void* d_ws, size_t ws_size,
                              hipStream_t stream) {
    const int*   seq    = (const int*)d_in[0];
    const float* emb    = (const float*)d_in[2];
    const float* mog1_W = (const float*)d_in[3];
    const float* mog1_b = (const float*)d_in[4];
    const float* W_ih1  = (const float*)d_in[5];
    const float* W_hh1  = (const float*)d_in[6];
    const float* b_ih1  = (const float*)d_in[7];
    const float* b_hh1  = (const float*)d_in[8];
    const float* mog2_W = (const float*)d_in[9];
    const float* mog2_b = (const float*)d_in[10];
    const float* W_ih2  = (const float*)d_in[11];
    const float* W_hh2  = (const float*)d_in[12];
    const float* b_ih2  = (const float*)d_in[13];
    const float* b_hh2  = (const float*)d_in[14];
    const float* fc_b   = (const float*)d_in[15];

    char* ws = (char*)d_ws;
    float* XT = (float*)ws;                                  // 64 x 32768 floats = 8 MB
    float* st = (float*)(ws + 8388608);                      // 8 x 32768 floats = 1 MB
    unsigned* bar = (unsigned*)(ws + 9437184);               // 4 KB
    unsigned short* hsb = (unsigned short*)(ws + 9441280);   // 4 MB

    float* out0 = (float*)d_out;
    float* hs   = out0 + 65536000LL;

    hipMemsetAsync(st, 0, 524288, stream);    // h1,c1,h2,c2 = 0
    hipMemsetAsync(bar, 0, 256, stream);

    gather_embed<<<64, 256, 0, stream>>>(seq, emb, XT);

    RArgs a;
    a.m1W = mog1_W; a.m1b = mog1_b;
    a.Wih1 = W_ih1; a.Whh1 = W_hh1; a.bih1 = b_ih1; a.bhh1 = b_hh1;
    a.m2W = mog2_W; a.m2b = mog2_b;
    a.Wih2 = W_ih2; a.Whh2 = W_hh2; a.bih2 = b_ih2; a.bhh2 = b_hh2;
    a.XT = XT; a.st = st; a.hs = hs; a.bar = bar;

    reck<<<512, 256, 0, stream>>>(a);

    f32_to_bf16<<<1024, 256, 0, stream>>>(hs, hsb, 2097152);
    out_proj<<<dim3(250, 16), 256, 0, stream>>>(hsb, emb, fc_b, out0);
}

// Round 3
// 13274.184 us; speedup vs baseline: 2.0613x; 2.0613x over previous
//
#include <hip/hip_runtime.h>

typedef short bf16x8 __attribute__((ext_vector_type(8)));
typedef float f32x4 __attribute__((ext_vector_type(4)));

static __device__ __forceinline__ unsigned short f2bf(float f) {
    unsigned int u = __float_as_uint(f);
    unsigned int r = (u + 0x7fffu + ((u >> 16) & 1u)) >> 16;
    return (unsigned short)r;
}
static __device__ __forceinline__ float sigmoidf_(float x) {
    return 1.0f / (1.0f + __expf(-x));
}
static __device__ __forceinline__ float tanhf_(float x) {
    return 2.0f / (1.0f + __expf(-2.0f * x)) - 1.0f;
}

// async global -> LDS, 16 B per lane. lds ptr must be wave-uniform base; HW adds lane*16.
static __device__ __forceinline__ void dma16(const float* g, float* l) {
    __builtin_amdgcn_global_load_lds((const __attribute__((address_space(1))) void*)g,
                                     (__attribute__((address_space(3))) void*)l, 16, 0, 0);
}

// ---- activation layout: element (k,b) at ((k>>2)*32 + b)*4 + (k&3)  (k4-interleaved) ----

// ---------------- grid barrier: relaxed spin + one acquire fence ----------------
static __device__ __forceinline__ void gbar(unsigned* bar, int nb) {
    asm volatile("s_waitcnt vmcnt(0) lgkmcnt(0)" ::: "memory");
    __builtin_amdgcn_s_barrier();
    if (threadIdx.x == 0) {
        unsigned* gen = bar + 32;
        unsigned gv = __hip_atomic_load(gen, __ATOMIC_RELAXED, __HIP_MEMORY_SCOPE_AGENT);
        unsigned a = __hip_atomic_fetch_add(bar, 1u, __ATOMIC_ACQ_REL, __HIP_MEMORY_SCOPE_AGENT);
        if (a == (unsigned)nb - 1u) {
            __hip_atomic_store(bar, 0u, __ATOMIC_RELAXED, __HIP_MEMORY_SCOPE_AGENT);
            __hip_atomic_store(gen, gv + 1u, __ATOMIC_RELEASE, __HIP_MEMORY_SCOPE_AGENT);
        } else {
            while (__hip_atomic_load(gen, __ATOMIC_RELAXED, __HIP_MEMORY_SCOPE_AGENT) == gv)
                __builtin_amdgcn_s_sleep(2);
        }
        __builtin_amdgcn_fence(__ATOMIC_ACQUIRE, "agent");
    }
    __builtin_amdgcn_s_barrier();
}

// ---------------- persistent recurrence kernel ----------------
struct RArgs {
    const float *m1W, *m1b, *Wih1, *Whh1, *bih1, *bhh1;
    const float *m2W, *m2b, *Wih2, *Whh2, *bih2, *bhh2;
    float *XT, *st, *hs;
    unsigned* bar;
};

__global__ __launch_bounds__(256, 2) void reck(RArgs A) {
    __shared__ float wbuf[2][4096];   // 32 KB: mog weight double-buffer / lstm chunk buf P
    __shared__ float lext[4096];      // 16 KB: lstm chunk buf Q
    __shared__ float red2[4][16][32]; // 8 KB reduction scratch

    const int tid = threadIdx.x;
    const int lane = tid & 63;
    const int wv = tid >> 6;
    const int b = tid & 31;
    const int kq = tid >> 5;          // 0..7
    const int blk = blockIdx.x;
    const bool L1 = blk < 256;
    const int g = L1 ? blk : blk - 256;
    const int j0 = g * 4;

    const float* mW  = L1 ? A.m1W : A.m2W;
    const float* mb  = L1 ? A.m1b : A.m2b;
    const float* Wih = L1 ? A.Wih1 : A.Wih2;
    const float* Whh = L1 ? A.Whh1 : A.Whh2;
    const float* bih = L1 ? A.bih1 : A.bih2;
    const float* bhh = L1 ? A.bhh1 : A.bhh2;

    float* h   = A.st + (L1 ? 0 : 65536);
    float* cc  = A.st + (L1 ? 32768 : 98304);
    float* hm  = A.st + (L1 ? 131072 : 163840);
    float* x2v = A.st + 196608;

    // prologue: mog phase-0 weights -> wbuf[0]
    {
        const float* src = mW + (size_t)j0 * 1024 + wv * 1024;
        float* dl = &wbuf[0][wv * 1024];
#pragma unroll
        for (int i = 0; i < 4; ++i) dma16(src + i * 256 + lane * 4, dl + i * 256);
    }
    asm volatile("s_waitcnt vmcnt(0)" ::: "memory");
    __builtin_amdgcn_s_barrier();

    int cur = 0;
    for (int s = 0; s <= 64; ++s) {
        const bool act = L1 ? (s < 64) : (s > 0);
        const int t = L1 ? s : s - 1;
        float* x = L1 ? (A.XT + (size_t)(act ? t : 0) * 32768)
                      : (x2v + (size_t)((act ? t : 0) & 1) * 32768);

        for (int ph = 0; ph < 5; ++ph) {
            // issue next mog-phase weight DMA into the other buffer (in flight across compute+barrier)
            {
                const float* src = mW + (size_t)((ph + 1) % 5) * 1048576
                                      + (size_t)j0 * 1024 + wv * 1024;
                float* dl = &wbuf[cur ^ 1][wv * 1024];
#pragma unroll
                for (int i = 0; i < 4; ++i) dma16(src + i * 256 + lane * 4, dl + i * 256);
            }
            if (act) {
                const float *gin, *srcv; float* dstv;
                switch (ph) {
                    default:
                    case 0: gin = h;  srcv = x;  dstv = x;  break;
                    case 1: gin = x;  srcv = h;  dstv = hm; break;
                    case 2: gin = hm; srcv = x;  dstv = x;  break;
                    case 3: gin = x;  srcv = hm; dstv = hm; break;
                    case 4: gin = hm; srcv = x;  dstv = x;  break;
                }
                const float* gp = gin + kq * 4096 + b * 4;
                const float* wl = &wbuf[cur][kq * 128];
                float a0 = 0.f, a1 = 0.f, a2 = 0.f, a3 = 0.f;
#pragma unroll 8
                for (int c2 = 0; c2 < 32; ++c2) {
                    float4 a = *(const float4*)(gp + c2 * 128);
                    float4 w = *(const float4*)(wl + c2 * 4);
                    a0 += a.x * w.x + a.y * w.y + a.z * w.z + a.w * w.w;
                    w = *(const float4*)(wl + 1024 + c2 * 4);
                    a1 += a.x * w.x + a.y * w.y + a.z * w.z + a.w * w.w;
                    w = *(const float4*)(wl + 2048 + c2 * 4);
                    a2 += a.x * w.x + a.y * w.y + a.z * w.z + a.w * w.w;
                    w = *(const float4*)(wl + 3072 + c2 * 4);
                    a3 += a.x * w.x + a.y * w.y + a.z * w.z + a.w * w.w;
                }
                a0 += __shfl_xor(a0, 32);
                a1 += __shfl_xor(a1, 32);
                a2 += __shfl_xor(a2, 32);
                a3 += __shfl_xor(a3, 32);
                if ((tid & 32) == 0) {
                    red2[wv][0][b] = a0; red2[wv][1][b] = a1;
                    red2[wv][2][b] = a2; red2[wv][3][b] = a3;
                }
                __syncthreads();
                if (tid < 128) {
                    int j = tid >> 5, bb = tid & 31;
                    float ssum = (red2[0][j][bb] + red2[1][j][bb])
                               + (red2[2][j][bb] + red2[3][j][bb]);
                    int ja = j0 + j;
                    ssum += mb[ph * 1024 + ja];
                    float gmul = 2.0f * sigmoidf_(ssum);
                    int idx = ((ja >> 2) * 32 + bb) * 4 + (ja & 3);
                    dstv[idx] = gmul * srcv[idx];
                }
            }
            gbar(A.bar, (int)gridDim.x);
            cur ^= 1;
        }

        // ---------------- LSTM slot: stream 8x16KB weight chunks through LDS ----------------
        {
            float* P = &wbuf[cur ^ 1][0];
            float* Q = &lext[0];
            if (act) {
                // chunk c: side = c>>2 (0:Wih/x, 1:Whh/hm), kseg = c&3 (256 k each)
                // wave wv DMAs rows rr = wv*4+i ; row R = (rr>>2)*1024 + j0 + (rr&3)
                {
                    const float* WS = Wih;
#pragma unroll
                    for (int i = 0; i < 4; ++i) {
                        int rr = wv * 4 + i;
                        int R = (rr >> 2) * 1024 + j0 + (rr & 3);
                        dma16(WS + (size_t)R * 1024 + lane * 4, Q + rr * 256);
                    }
                }
                asm volatile("s_waitcnt vmcnt(0)" ::: "memory");
                __builtin_amdgcn_s_barrier();

                float acc[16];
#pragma unroll
                for (int i = 0; i < 16; ++i) acc[i] = 0.f;

                for (int c = 0; c < 8; ++c) {
                    float* bc = (c & 1) ? P : Q;
                    const int side = c >> 2, kseg = c & 3;
                    const float* ab = (side ? hm : x) + (size_t)(kseg * 64 + kq * 8) * 128 + b * 4;
                    float4 av[8];
#pragma unroll
                    for (int i = 0; i < 8; ++i) av[i] = *(const float4*)(ab + i * 128);
                    __builtin_amdgcn_sched_barrier(0);
                    if (c < 7) {
                        const int cn = c + 1;
                        const int nside = cn >> 2, nkseg = cn & 3;
                        const float* WS = nside ? Whh : Wih;
                        float* nb2 = (c & 1) ? Q : P;
#pragma unroll
                        for (int i = 0; i < 4; ++i) {
                            int rr = wv * 4 + i;
                            int R = (rr >> 2) * 1024 + j0 + (rr & 3);
                            dma16(WS + (size_t)R * 1024 + nkseg * 256 + lane * 4, nb2 + rr * 256);
                        }
                    }
                    __builtin_amdgcn_sched_barrier(0);
#pragma unroll
                    for (int i = 0; i < 8; ++i) {
#pragma unroll
                        for (int rr = 0; rr < 16; ++rr) {
                            float4 w = *(const float4*)(bc + rr * 256 + kq * 32 + i * 4);
                            acc[rr] += av[i].x * w.x + av[i].y * w.y
                                     + av[i].z * w.z + av[i].w * w.w;
                        }
                    }
                    asm volatile("s_waitcnt vmcnt(0) lgkmcnt(0)" ::: "memory");
                    __builtin_amdgcn_s_barrier();
                }

#pragma unroll
                for (int i = 0; i < 16; ++i) acc[i] += __shfl_xor(acc[i], 32);
                if ((tid & 32) == 0) {
#pragma unroll
                    for (int i = 0; i < 16; ++i) red2[wv][i][b] = acc[i];
                }
                __syncthreads();
                if (tid < 128) {
                    int jj = tid >> 5, bb = tid & 31;
                    int ja = j0 + jj;
                    float gi = 0.f, gf = 0.f, gg = 0.f, go = 0.f;
#pragma unroll
                    for (int w = 0; w < 4; ++w) {
                        gi += red2[w][0 + jj][bb];
                        gf += red2[w][4 + jj][bb];
                        gg += red2[w][8 + jj][bb];
                        go += red2[w][12 + jj][bb];
                    }
                    gi += bih[ja] + bhh[ja];
                    gf += bih[1024 + ja] + bhh[1024 + ja];
                    gg += bih[2048 + ja] + bhh[2048 + ja];
                    go += bih[3072 + ja] + bhh[3072 + ja];
                    int idx = ((ja >> 2) * 32 + bb) * 4 + (ja & 3);
                    float cn = sigmoidf_(gf) * cc[idx] + sigmoidf_(gi) * tanhf_(gg);
                    cc[idx] = cn;
                    float hn = sigmoidf_(go) * tanhf_(cn);
                    h[idx] = hn;
                    if (L1) {
                        x2v[(size_t)(t & 1) * 32768 + idx] = hn;
                    } else {
                        A.hs[(size_t)bb * 65536 + (size_t)t * 1024 + ja] = hn;
                    }
                }
            }
            gbar(A.bar, (int)gridDim.x);
        }
    }
}

// ---------------- embedding gather into k4-interleaved layout ----------------
__global__ __launch_bounds__(256) void gather_embed(const int* __restrict__ seq,
                                                    const float* __restrict__ emb,
                                                    float* __restrict__ XT) {
    int t = blockIdx.x;
    const float4* emb4 = (const float4*)emb;
    float4* xt4 = (float4*)(XT + (size_t)t * 32768);
#pragma unroll 4
    for (int b = 0; b < 32; ++b) {
        int row = seq[b * 64 + t];
        float4 v = emb4[(size_t)row * 256 + threadIdx.x];
        xt4[threadIdx.x * 32 + b] = v;
    }
}

// ---------------- fp32 -> bf16 ----------------
__global__ __launch_bounds__(256) void f32_to_bf16(const float* __restrict__ in,
                                                   unsigned short* __restrict__ out, int n) {
    int i = (blockIdx.x * 256 + threadIdx.x) * 8;
    if (i + 7 < n) {
        float4 f0 = *(const float4*)(in + i);
        float4 f1 = *(const float4*)(in + i + 4);
        bf16x8 v;
        v[0] = (short)f2bf(f0.x); v[1] = (short)f2bf(f0.y);
        v[2] = (short)f2bf(f0.z); v[3] = (short)f2bf(f0.w);
        v[4] = (short)f2bf(f1.x); v[5] = (short)f2bf(f1.y);
        v[6] = (short)f2bf(f1.z); v[7] = (short)f2bf(f1.w);
        *(bf16x8*)(out + i) = v;
    }
}

// ---------------- output projection (bf16 MFMA, 128x128 tile) ----------------
__global__ __launch_bounds__(256) void out_proj(const unsigned short* __restrict__ hsb,
                                                const float* __restrict__ emb,
                                                const float* __restrict__ fcb,
                                                float* __restrict__ out) {
    __shared__ unsigned short Al[128 * 40];
    __shared__ unsigned short Bl[128 * 40];
    int tid = threadIdx.x;
    int n0 = blockIdx.x * 128;
    int m0 = blockIdx.y * 128;
    int wid = tid >> 6, l = tid & 63;
    int wm = wid >> 1, wn = wid & 1;
    int c16 = l & 15, kg = l >> 4;

    f32x4 acc[4][4];
#pragma unroll
    for (int i = 0; i < 4; i++)
#pragma unroll
        for (int j = 0; j < 4; j++) acc[i][j] = (f32x4){0.f, 0.f, 0.f, 0.f};

    for (int k0 = 0; k0 < 1024; k0 += 32) {
#pragma unroll
        for (int i = 0; i < 2; i++) {
            int id = i * 256 + tid;
            int r = id >> 2, ccc = id & 3;
            *(bf16x8*)&Al[r * 40 + ccc * 8] =
                *(const bf16x8*)(hsb + (size_t)(m0 + r) * 1024 + k0 + ccc * 8);
        }
#pragma unroll
        for (int i = 0; i < 2; i++) {
            int id = i * 256 + tid;
            int r = id >> 2, ccc = id & 3;
            const float* src = emb + (size_t)(n0 + r) * 1024 + k0 + ccc * 8;
            float4 f0 = *(const float4*)(src);
            float4 f1 = *(const float4*)(src + 4);
            bf16x8 v;
            v[0] = (short)f2bf(f0.x); v[1] = (short)f2bf(f0.y);
            v[2] = (short)f2bf(f0.z); v[3] = (short)f2bf(f0.w);
            v[4] = (short)f2bf(f1.x); v[5] = (short)f2bf(f1.y);
            v[6] = (short)f2bf(f1.z); v[7] = (short)f2bf(f1.w);
            *(bf16x8*)&Bl[r * 40 + ccc * 8] = v;
        }
        __syncthreads();

        bf16x8 afr[4], bfr[4];
#pragma unroll
        for (int i = 0; i < 4; i++)
            afr[i] = *(const bf16x8*)&Al[(wm * 64 + i * 16 + c16) * 40 + kg * 8];
#pragma unroll
        for (int j = 0; j < 4; j++)
            bfr[j] = *(const bf16x8*)&Bl[(wn * 64 + j * 16 + c16) * 40 + kg * 8];
#pragma unroll
        for (int i = 0; i < 4; i++)
#pragma unroll
            for (int j = 0; j < 4; j++)
                acc[i][j] = __builtin_amdgcn_mfma_f32_16x16x32_bf16(afr[i], bfr[j], acc[i][j], 0, 0, 0);
        __syncthreads();
    }

#pragma unroll
    for (int i = 0; i < 4; i++) {
        int row = m0 + wm * 64 + i * 16 + kg * 4;
#pragma unroll
        for (int j = 0; j < 4; j++) {
            int col = n0 + wn * 64 + j * 16 + c16;
            float fb = fcb[col];
#pragma unroll
            for (int r = 0; r < 4; r++)
                out[(size_t)(row + r) * 32000 + col] = acc[i][j][r] + fb;
        }
    }
}

// ---------------- host ----------------
extern "C" void kernel_launch(void* const* d_in, const int* in_sizes, int n_in,
                              void* d_out, int out_size, void* d_ws, size_t ws_size,
                              hipStream_t stream) {
    const int*   seq    = (const int*)d_in[0];
    const float* emb    = (const float*)d_in[2];
    const float* mog1_W = (const float*)d_in[3];
    const float* mog1_b = (const float*)d_in[4];
    const float* W_ih1  = (const float*)d_in[5];
    const float* W_hh1  = (const float*)d_in[6];
    const float* b_ih1  = (const float*)d_in[7];
    const float* b_hh1  = (const float*)d_in[8];
    const float* mog2_W = (const float*)d_in[9];
    const float* mog2_b = (const float*)d_in[10];
    const float* W_ih2  = (const float*)d_in[11];
    const float* W_hh2  = (const float*)d_in[12];
    const float* b_ih2  = (const float*)d_in[13];
    const float* b_hh2  = (const float*)d_in[14];
    const float* fc_b   = (const float*)d_in[15];

    char* ws = (char*)d_ws;
    float* XT = (float*)ws;                                  // 8 MB
    float* st = (float*)(ws + 8388608);                      // 1 MB
    unsigned* bar = (unsigned*)(ws + 9437184);               // 4 KB
    unsigned short* hsb = (unsigned short*)(ws + 9441280);   // 4 MB

    float* out0 = (float*)d_out;
    float* hs   = out0 + 65536000LL;

    hipMemsetAsync(st, 0, 524288, stream);
    hipMemsetAsync(bar, 0, 256, stream);

    gather_embed<<<64, 256, 0, stream>>>(seq, emb, XT);

    RArgs a;
    a.m1W = mog1_W; a.m1b = mog1_b;
    a.Wih1 = W_ih1; a.Whh1 = W_hh1; a.bih1 = b_ih1; a.bhh1 = b_hh1;
    a.m2W = mog2_W; a.m2b = mog2_b;
    a.Wih2 = W_ih2; a.Whh2 = W_hh2; a.bih2 = b_ih2; a.bhh2 = b_hh2;
    a.XT = XT; a.st = st; a.hs = hs; a.bar = bar;

    reck<<<512, 256, 0, stream>>>(a);

    f32_to_bf16<<<1024, 256, 0, stream>>>(hs, hsb, 2097152);
    out_proj<<<dim3(250, 16), 256, 0, stream>>>(hsb, emb, fc_b, out0);
}

// Round 4
// 9817.547 us; speedup vs baseline: 2.7871x; 1.3521x over previous
//
#include <hip/hip_runtime.h>

typedef short bf16x8 __attribute__((ext_vector_type(8)));
typedef float f32x4 __attribute__((ext_vector_type(4)));

static __device__ __forceinline__ unsigned short f2bf(float f) {
    unsigned int u = __float_as_uint(f);
    unsigned int r = (u + 0x7fffu + ((u >> 16) & 1u)) >> 16;
    return (unsigned short)r;
}
static __device__ __forceinline__ float sigmoidf_(float x) {
    return 1.0f / (1.0f + __expf(-x));
}
static __device__ __forceinline__ float tanhf_(float x) {
    return 2.0f / (1.0f + __expf(-2.0f * x)) - 1.0f;
}

// async global -> LDS, 16 B per lane. lds ptr must be wave-uniform base; HW adds lane*16.
static __device__ __forceinline__ void dma16(const float* g, float* l) {
    __builtin_amdgcn_global_load_lds((const __attribute__((address_space(1))) void*)g,
                                     (__attribute__((address_space(3))) void*)l, 16, 0, 0);
}

// ---- activation layout: element (k,b) at ((k>>2)*32 + b)*4 + (k&3)  (k4-interleaved) ----

// ---------------- grid barrier: 64 distributed arrival counters (128B apart, monotonic),
// master block 0 wave-0 sums them, releases a generation word. ----------------
// bar layout (uint): cnt[i] at bar[i*32], i=0..63 ; gen at bar[2048]
static __device__ __forceinline__ void gbar(unsigned* bar, unsigned target) {
    asm volatile("s_waitcnt vmcnt(0) lgkmcnt(0)" ::: "memory");
    __builtin_amdgcn_s_barrier();
    const int tid = threadIdx.x;
    if (tid == 0) {
        __hip_atomic_fetch_add(bar + ((blockIdx.x & 63) << 5), 1u,
                               __ATOMIC_RELEASE, __HIP_MEMORY_SCOPE_AGENT);
    }
    if (blockIdx.x == 0) {
        if (tid < 64) {
            const unsigned tgt = target << 9;   // 512 * target
            for (;;) {
                unsigned v = __hip_atomic_load(bar + (tid << 5), __ATOMIC_RELAXED,
                                               __HIP_MEMORY_SCOPE_AGENT);
                v += __shfl_xor(v, 1);
                v += __shfl_xor(v, 2);
                v += __shfl_xor(v, 4);
                v += __shfl_xor(v, 8);
                v += __shfl_xor(v, 16);
                v += __shfl_xor(v, 32);
                if (v >= tgt) break;
            }
            if (tid == 0) {
                __hip_atomic_store(bar + 2048, target, __ATOMIC_RELEASE,
                                   __HIP_MEMORY_SCOPE_AGENT);
                __builtin_amdgcn_fence(__ATOMIC_ACQUIRE, "agent");
            }
        }
    } else {
        if (tid == 0) {
            while (__hip_atomic_load(bar + 2048, __ATOMIC_RELAXED,
                                     __HIP_MEMORY_SCOPE_AGENT) < target)
                __builtin_amdgcn_s_sleep(1);
            __builtin_amdgcn_fence(__ATOMIC_ACQUIRE, "agent");
        }
    }
    __builtin_amdgcn_s_barrier();
}

// ---------------- persistent recurrence kernel ----------------
struct RArgs {
    const float *m1W, *m1b, *Wih1, *Whh1, *bih1, *bhh1;
    const float *m2W, *m2b, *Wih2, *Whh2, *bih2, *bhh2;
    float *XT, *st, *hs;
    unsigned* bar;
};

__global__ __launch_bounds__(256, 2) void reck(RArgs A) {
    __shared__ float wbuf[2][4096];   // 32 KB: mog weight double-buffer / lstm chunk buf P
    __shared__ float lext[4096];      // 16 KB: lstm chunk buf Q
    __shared__ float red2[4][16][32]; // 8 KB reduction scratch

    const int tid = threadIdx.x;
    const int lane = tid & 63;
    const int wv = tid >> 6;
    const int b = tid & 31;
    const int kq = tid >> 5;          // 0..7
    const int blk = blockIdx.x;
    const bool L1 = blk < 256;
    const int g = L1 ? blk : blk - 256;
    const int j0 = g * 4;

    const float* mW  = L1 ? A.m1W : A.m2W;
    const float* mb  = L1 ? A.m1b : A.m2b;
    const float* Wih = L1 ? A.Wih1 : A.Wih2;
    const float* Whh = L1 ? A.Whh1 : A.Whh2;
    const float* bih = L1 ? A.bih1 : A.bih2;
    const float* bhh = L1 ? A.bhh1 : A.bhh2;

    float* h   = A.st + (L1 ? 0 : 65536);
    float* cc  = A.st + (L1 ? 32768 : 98304);
    float* hm  = A.st + (L1 ? 131072 : 163840);
    float* x2v = A.st + 196608;

    // prologue: mog phase-0 weights -> wbuf[0]
    {
        const float* src = mW + (size_t)j0 * 1024 + wv * 1024;
        float* dl = &wbuf[0][wv * 1024];
#pragma unroll
        for (int i = 0; i < 4; ++i) dma16(src + i * 256 + lane * 4, dl + i * 256);
    }
    asm volatile("s_waitcnt vmcnt(0)" ::: "memory");
    __builtin_amdgcn_s_barrier();

    unsigned bcnt = 0;
    int cur = 0;
    for (int s = 0; s <= 64; ++s) {
        const bool act = L1 ? (s < 64) : (s > 0);
        const int t = L1 ? s : s - 1;
        float* x = L1 ? (A.XT + (size_t)(act ? t : 0) * 32768)
                      : (x2v + (size_t)((act ? t : 0) & 1) * 32768);

        for (int ph = 0; ph < 5; ++ph) {
            // issue next mog-phase weight DMA into the other buffer (in flight across compute+barrier)
            {
                const float* src = mW + (size_t)((ph + 1) % 5) * 1048576
                                      + (size_t)j0 * 1024 + wv * 1024;
                float* dl = &wbuf[cur ^ 1][wv * 1024];
#pragma unroll
                for (int i = 0; i < 4; ++i) dma16(src + i * 256 + lane * 4, dl + i * 256);
            }
            if (act) {
                const float *gin, *srcv; float* dstv;
                switch (ph) {
                    default:
                    case 0: gin = h;  srcv = x;  dstv = x;  break;
                    case 1: gin = x;  srcv = h;  dstv = hm; break;
                    case 2: gin = hm; srcv = x;  dstv = x;  break;
                    case 3: gin = x;  srcv = hm; dstv = hm; break;
                    case 4: gin = hm; srcv = x;  dstv = x;  break;
                }
                const float* gp = gin + kq * 4096 + b * 4;
                const float* wl = &wbuf[cur][kq * 128];
                float a0 = 0.f, a1 = 0.f, a2 = 0.f, a3 = 0.f;
#pragma unroll 8
                for (int c2 = 0; c2 < 32; ++c2) {
                    float4 a = *(const float4*)(gp + c2 * 128);
                    float4 w = *(const float4*)(wl + c2 * 4);
                    a0 += a.x * w.x + a.y * w.y + a.z * w.z + a.w * w.w;
                    w = *(const float4*)(wl + 1024 + c2 * 4);
                    a1 += a.x * w.x + a.y * w.y + a.z * w.z + a.w * w.w;
                    w = *(const float4*)(wl + 2048 + c2 * 4);
                    a2 += a.x * w.x + a.y * w.y + a.z * w.z + a.w * w.w;
                    w = *(const float4*)(wl + 3072 + c2 * 4);
                    a3 += a.x * w.x + a.y * w.y + a.z * w.z + a.w * w.w;
                }
                a0 += __shfl_xor(a0, 32);
                a1 += __shfl_xor(a1, 32);
                a2 += __shfl_xor(a2, 32);
                a3 += __shfl_xor(a3, 32);
                if ((tid & 32) == 0) {
                    red2[wv][0][b] = a0; red2[wv][1][b] = a1;
                    red2[wv][2][b] = a2; red2[wv][3][b] = a3;
                }
                __syncthreads();
                if (tid < 128) {
                    int j = tid >> 5, bb = tid & 31;
                    float ssum = (red2[0][j][bb] + red2[1][j][bb])
                               + (red2[2][j][bb] + red2[3][j][bb]);
                    int ja = j0 + j;
                    ssum += mb[ph * 1024 + ja];
                    float gmul = 2.0f * sigmoidf_(ssum);
                    int idx = ((ja >> 2) * 32 + bb) * 4 + (ja & 3);
                    dstv[idx] = gmul * srcv[idx];
                }
            }
            gbar(A.bar, ++bcnt);
            cur ^= 1;
        }

        // ---------------- LSTM slot: stream 8x16KB weight chunks through LDS ----------------
        {
            float* P = &wbuf[cur ^ 1][0];
            float* Q = &lext[0];
            if (act) {
                // chunk c: side = c>>2 (0:Wih/x, 1:Whh/hm), kseg = c&3 (256 k each)
                // wave wv DMAs rows rr = wv*4+i ; row R = (rr>>2)*1024 + j0 + (rr&3)
                {
                    const float* WS = Wih;
#pragma unroll
                    for (int i = 0; i < 4; ++i) {
                        int rr = wv * 4 + i;
                        int R = (rr >> 2) * 1024 + j0 + (rr & 3);
                        dma16(WS + (size_t)R * 1024 + lane * 4, Q + rr * 256);
                    }
                }
                asm volatile("s_waitcnt vmcnt(0)" ::: "memory");
                __builtin_amdgcn_s_barrier();

                float acc[16];
#pragma unroll
                for (int i = 0; i < 16; ++i) acc[i] = 0.f;

                for (int c = 0; c < 8; ++c) {
                    float* bc = (c & 1) ? P : Q;
                    const int side = c >> 2, kseg = c & 3;
                    const float* ab = (side ? hm : x) + (size_t)(kseg * 64 + kq * 8) * 128 + b * 4;
                    float4 av[8];
#pragma unroll
                    for (int i = 0; i < 8; ++i) av[i] = *(const float4*)(ab + i * 128);
                    __builtin_amdgcn_sched_barrier(0);
                    if (c < 7) {
                        const int cn = c + 1;
                        const int nside = cn >> 2, nkseg = cn & 3;
                        const float* WS = nside ? Whh : Wih;
                        float* nb2 = (c & 1) ? Q : P;
#pragma unroll
                        for (int i = 0; i < 4; ++i) {
                            int rr = wv * 4 + i;
                            int R = (rr >> 2) * 1024 + j0 + (rr & 3);
                            dma16(WS + (size_t)R * 1024 + nkseg * 256 + lane * 4, nb2 + rr * 256);
                        }
                    }
                    __builtin_amdgcn_sched_barrier(0);
#pragma unroll
                    for (int i = 0; i < 8; ++i) {
#pragma unroll
                        for (int rr = 0; rr < 16; ++rr) {
                            float4 w = *(const float4*)(bc + rr * 256 + kq * 32 + i * 4);
                            acc[rr] += av[i].x * w.x + av[i].y * w.y
                                     + av[i].z * w.z + av[i].w * w.w;
                        }
                    }
                    asm volatile("s_waitcnt vmcnt(0) lgkmcnt(0)" ::: "memory");
                    __builtin_amdgcn_s_barrier();
                }

#pragma unroll
                for (int i = 0; i < 16; ++i) acc[i] += __shfl_xor(acc[i], 32);
                if ((tid & 32) == 0) {
#pragma unroll
                    for (int i = 0; i < 16; ++i) red2[wv][i][b] = acc[i];
                }
                __syncthreads();
                if (tid < 128) {
                    int jj = tid >> 5, bb = tid & 31;
                    int ja = j0 + jj;
                    float gi = 0.f, gf = 0.f, gg = 0.f, go = 0.f;
#pragma unroll
                    for (int w = 0; w < 4; ++w) {
                        gi += red2[w][0 + jj][bb];
                        gf += red2[w][4 + jj][bb];
                        gg += red2[w][8 + jj][bb];
                        go += red2[w][12 + jj][bb];
                    }
                    gi += bih[ja] + bhh[ja];
                    gf += bih[1024 + ja] + bhh[1024 + ja];
                    gg += bih[2048 + ja] + bhh[2048 + ja];
                    go += bih[3072 + ja] + bhh[3072 + ja];
                    int idx = ((ja >> 2) * 32 + bb) * 4 + (ja & 3);
                    float cn = sigmoidf_(gf) * cc[idx] + sigmoidf_(gi) * tanhf_(gg);
                    cc[idx] = cn;
                    float hn = sigmoidf_(go) * tanhf_(cn);
                    h[idx] = hn;
                    if (L1) {
                        x2v[(size_t)(t & 1) * 32768 + idx] = hn;
                    } else {
                        A.hs[(size_t)bb * 65536 + (size_t)t * 1024 + ja] = hn;
                    }
                }
            }
            gbar(A.bar, ++bcnt);
        }
    }
}

// ---------------- embedding gather into k4-interleaved layout ----------------
__global__ __launch_bounds__(256) void gather_embed(const int* __restrict__ seq,
                                                    const float* __restrict__ emb,
                                                    float* __restrict__ XT) {
    int t = blockIdx.x;
    const float4* emb4 = (const float4*)emb;
    float4* xt4 = (float4*)(XT + (size_t)t * 32768);
#pragma unroll 4
    for (int b = 0; b < 32; ++b) {
        int row = seq[b * 64 + t];
        float4 v = emb4[(size_t)row * 256 + threadIdx.x];
        xt4[threadIdx.x * 32 + b] = v;
    }
}

// ---------------- fp32 -> bf16 ----------------
__global__ __launch_bounds__(256) void f32_to_bf16(const float* __restrict__ in,
                                                   unsigned short* __restrict__ out, int n) {
    int i = (blockIdx.x * 256 + threadIdx.x) * 8;
    if (i + 7 < n) {
        float4 f0 = *(const float4*)(in + i);
        float4 f1 = *(const float4*)(in + i + 4);
        bf16x8 v;
        v[0] = (short)f2bf(f0.x); v[1] = (short)f2bf(f0.y);
        v[2] = (short)f2bf(f0.z); v[3] = (short)f2bf(f0.w);
        v[4] = (short)f2bf(f1.x); v[5] = (short)f2bf(f1.y);
        v[6] = (short)f2bf(f1.z); v[7] = (short)f2bf(f1.w);
        *(bf16x8*)(out + i) = v;
    }
}

// ---------------- output projection (bf16 MFMA, 128x128 tile) ----------------
__global__ __launch_bounds__(256) void out_proj(const unsigned short* __restrict__ hsb,
                                                const float* __restrict__ emb,
                                                const float* __restrict__ fcb,
                                                float* __restrict__ out) {
    __shared__ unsigned short Al[128 * 40];
    __shared__ unsigned short Bl[128 * 40];
    int tid = threadIdx.x;
    int n0 = blockIdx.x * 128;
    int m0 = blockIdx.y * 128;
    int wid = tid >> 6, l = tid & 63;
    int wm = wid >> 1, wn = wid & 1;
    int c16 = l & 15, kg = l >> 4;

    f32x4 acc[4][4];
#pragma unroll
    for (int i = 0; i < 4; i++)
#pragma unroll
        for (int j = 0; j < 4; j++) acc[i][j] = (f32x4){0.f, 0.f, 0.f, 0.f};

    for (int k0 = 0; k0 < 1024; k0 += 32) {
#pragma unroll
        for (int i = 0; i < 2; i++) {
            int id = i * 256 + tid;
            int r = id >> 2, ccc = id & 3;
            *(bf16x8*)&Al[r * 40 + ccc * 8] =
                *(const bf16x8*)(hsb + (size_t)(m0 + r) * 1024 + k0 + ccc * 8);
        }
#pragma unroll
        for (int i = 0; i < 2; i++) {
            int id = i * 256 + tid;
            int r = id >> 2, ccc = id & 3;
            const float* src = emb + (size_t)(n0 + r) * 1024 + k0 + ccc * 8;
            float4 f0 = *(const float4*)(src);
            float4 f1 = *(const float4*)(src + 4);
            bf16x8 v;
            v[0] = (short)f2bf(f0.x); v[1] = (short)f2bf(f0.y);
            v[2] = (short)f2bf(f0.z); v[3] = (short)f2bf(f0.w);
            v[4] = (short)f2bf(f1.x); v[5] = (short)f2bf(f1.y);
            v[6] = (short)f2bf(f1.z); v[7] = (short)f2bf(f1.w);
            *(bf16x8*)&Bl[r * 40 + ccc * 8] = v;
        }
        __syncthreads();

        bf16x8 afr[4], bfr[4];
#pragma unroll
        for (int i = 0; i < 4; i++)
            afr[i] = *(const bf16x8*)&Al[(wm * 64 + i * 16 + c16) * 40 + kg * 8];
#pragma unroll
        for (int j = 0; j < 4; j++)
            bfr[j] = *(const bf16x8*)&Bl[(wn * 64 + j * 16 + c16) * 40 + kg * 8];
#pragma unroll
        for (int i = 0; i < 4; i++)
#pragma unroll
            for (int j = 0; j < 4; j++)
                acc[i][j] = __builtin_amdgcn_mfma_f32_16x16x32_bf16(afr[i], bfr[j], acc[i][j], 0, 0, 0);
        __syncthreads();
    }

#pragma unroll
    for (int i = 0; i < 4; i++) {
        int row = m0 + wm * 64 + i * 16 + kg * 4;
#pragma unroll
        for (int j = 0; j < 4; j++) {
            int col = n0 + wn * 64 + j * 16 + c16;
            float fb = fcb[col];
#pragma unroll
            for (int r = 0; r < 4; r++)
                out[(size_t)(row + r) * 32000 + col] = acc[i][j][r] + fb;
        }
    }
}

// ---------------- host ----------------
extern "C" void kernel_launch(void* const* d_in, const int* in_sizes, int n_in,
                              void* d_out, int out_size, void* d_ws, size_t ws_size,
                              hipStream_t stream) {
    const int*   seq    = (const int*)d_in[0];
    const float* emb    = (const float*)d_in[2];
    const float* mog1_W = (const float*)d_in[3];
    const float* mog1_b = (const float*)d_in[4];
    const float* W_ih1  = (const float*)d_in[5];
    const float* W_hh1  = (const float*)d_in[6];
    const float* b_ih1  = (const float*)d_in[7];
    const float* b_hh1  = (const float*)d_in[8];
    const float* mog2_W = (const float*)d_in[9];
    const float* mog2_b = (const float*)d_in[10];
    const float* W_ih2  = (const float*)d_in[11];
    const float* W_hh2  = (const float*)d_in[12];
    const float* b_ih2  = (const float*)d_in[13];
    const float* b_hh2  = (const float*)d_in[14];
    const float* fc_b   = (const float*)d_in[15];

    char* ws = (char*)d_ws;
    float* XT = (float*)ws;                                  // 8 MB
    float* st = (float*)(ws + 8388608);                      // 1 MB
    unsigned* bar = (unsigned*)(ws + 9437184);               // 16 KB (64 padded counters + gen)
    unsigned short* hsb = (unsigned short*)(ws + 9453568);   // 4 MB

    float* out0 = (float*)d_out;
    float* hs   = out0 + 65536000LL;

    hipMemsetAsync(st, 0, 524288, stream);
    hipMemsetAsync(bar, 0, 16384, stream);

    gather_embed<<<64, 256, 0, stream>>>(seq, emb, XT);

    RArgs a;
    a.m1W = mog1_W; a.m1b = mog1_b;
    a.Wih1 = W_ih1; a.Whh1 = W_hh1; a.bih1 = b_ih1; a.bhh1 = b_hh1;
    a.m2W = mog2_W; a.m2b = mog2_b;
    a.Wih2 = W_ih2; a.Whh2 = W_hh2; a.bih2 = b_ih2; a.bhh2 = b_hh2;
    a.XT = XT; a.st = st; a.hs = hs; a.bar = bar;

    reck<<<512, 256, 0, stream>>>(a);

    f32_to_bf16<<<1024, 256, 0, stream>>>(hs, hsb, 2097152);
    out_proj<<<dim3(250, 16), 256, 0, stream>>>(hsb, emb, fc_b, out0);
}

// Round 5
// 6130.166 us; speedup vs baseline: 4.4635x; 1.6015x over previous
//
#include <hip/hip_runtime.h>

typedef short bf16x8 __attribute__((ext_vector_type(8)));
typedef float f32x4 __attribute__((ext_vector_type(4)));

static __device__ __forceinline__ unsigned short f2bf(float f) {
    unsigned int u = __float_as_uint(f);
    unsigned int r = (u + 0x7fffu + ((u >> 16) & 1u)) >> 16;
    return (unsigned short)r;
}
static __device__ __forceinline__ float sigmoidf_(float x) {
    return 1.0f / (1.0f + __expf(-x));
}
static __device__ __forceinline__ float tanhf_(float x) {
    return 2.0f / (1.0f + __expf(-2.0f * x)) - 1.0f;
}

// ---- device-coherent (agent-scope, uncached) activation access ----
static __device__ __forceinline__ float2 ldc8(const float* p) {
    unsigned long long u = __hip_atomic_load((unsigned long long*)p,
                                             __ATOMIC_RELAXED, __HIP_MEMORY_SCOPE_AGENT);
    float2 f;
    __builtin_memcpy(&f, &u, 8);
    return f;
}
static __device__ __forceinline__ float ldc4(const float* p) {
    unsigned u = __hip_atomic_load((unsigned*)p, __ATOMIC_RELAXED, __HIP_MEMORY_SCOPE_AGENT);
    return __uint_as_float(u);
}
static __device__ __forceinline__ void stc4(float* p, float v) {
    __hip_atomic_store((unsigned*)p, __float_as_uint(v),
                       __ATOMIC_RELAXED, __HIP_MEMORY_SCOPE_AGENT);
}

// async global -> LDS, 16 B per lane. lds ptr must be wave-uniform base; HW adds lane*16.
static __device__ __forceinline__ void dma16(const float* g, float* l) {
    __builtin_amdgcn_global_load_lds((const __attribute__((address_space(1))) void*)g,
                                     (__attribute__((address_space(3))) void*)l, 16, 0, 0);
}

// ---- activation layout: element (k,b) at ((k>>2)*32 + b)*4 + (k&3)  (k4-interleaved) ----

// ---------------- grid barrier: fence-free. 64 distributed arrival counters (128B apart,
// monotonic); master block 0 wave-0 sums, relaxed-releases a generation word. All data that
// crosses the barrier is itself device-coherent (sc1 atomics), so no cache fences needed. ----
// bar layout (uint): cnt[i] at bar[i*32], i=0..63 ; gen at bar[2048]
static __device__ __forceinline__ void gbar(unsigned* bar, unsigned target) {
    asm volatile("s_waitcnt vmcnt(0) lgkmcnt(0)" ::: "memory");
    __builtin_amdgcn_s_barrier();
    const int tid = threadIdx.x;
    if (tid == 0) {
        __hip_atomic_fetch_add(bar + ((blockIdx.x & 63) << 5), 1u,
                               __ATOMIC_RELAXED, __HIP_MEMORY_SCOPE_AGENT);
    }
    if (blockIdx.x == 0) {
        if (tid < 64) {
            const unsigned tgt = target << 9;   // 512 * target
            for (;;) {
                unsigned v = __hip_atomic_load(bar + (tid << 5), __ATOMIC_RELAXED,
                                               __HIP_MEMORY_SCOPE_AGENT);
                v += __shfl_xor(v, 1);
                v += __shfl_xor(v, 2);
                v += __shfl_xor(v, 4);
                v += __shfl_xor(v, 8);
                v += __shfl_xor(v, 16);
                v += __shfl_xor(v, 32);
                if (v >= tgt) break;
                __builtin_amdgcn_s_sleep(1);
            }
            if (tid == 0) {
                __hip_atomic_store(bar + 2048, target, __ATOMIC_RELAXED,
                                   __HIP_MEMORY_SCOPE_AGENT);
            }
        }
    } else {
        if (tid == 0) {
            while (__hip_atomic_load(bar + 2048, __ATOMIC_RELAXED,
                                     __HIP_MEMORY_SCOPE_AGENT) < target)
                __builtin_amdgcn_s_sleep(1);
        }
    }
    __builtin_amdgcn_s_barrier();
    asm volatile("" ::: "memory");
}

// ---------------- persistent recurrence kernel ----------------
struct RArgs {
    const float *m1W, *m1b, *Wih1, *Whh1, *bih1, *bhh1;
    const float *m2W, *m2b, *Wih2, *Whh2, *bih2, *bhh2;
    float *XT, *st, *hs;
    unsigned* bar;
};

__global__ __launch_bounds__(256, 2) void reck(RArgs A) {
    __shared__ float wbuf[2][4096];   // 32 KB: mog weight double-buffer / lstm chunk buf P
    __shared__ float lext[4096];      // 16 KB: lstm chunk buf Q
    __shared__ float red2[4][16][32]; // 8 KB reduction scratch

    const int tid = threadIdx.x;
    const int lane = tid & 63;
    const int wv = tid >> 6;
    const int b = tid & 31;
    const int kq = tid >> 5;          // 0..7
    const int blk = blockIdx.x;
    const bool L1 = blk < 256;
    const int g = L1 ? blk : blk - 256;
    const int j0 = g * 4;

    const float* mW  = L1 ? A.m1W : A.m2W;
    const float* mb  = L1 ? A.m1b : A.m2b;
    const float* Wih = L1 ? A.Wih1 : A.Wih2;
    const float* Whh = L1 ? A.Whh1 : A.Whh2;
    const float* bih = L1 ? A.bih1 : A.bih2;
    const float* bhh = L1 ? A.bhh1 : A.bhh2;

    float* h   = A.st + (L1 ? 0 : 65536);
    float* cc  = A.st + (L1 ? 32768 : 98304);   // block-local: stays normally cached
    float* hm  = A.st + (L1 ? 131072 : 163840);
    float* x2v = A.st + 196608;

    // prologue: mog phase-0 weights -> wbuf[0]
    {
        const float* src = mW + (size_t)j0 * 1024 + wv * 1024;
        float* dl = &wbuf[0][wv * 1024];
#pragma unroll
        for (int i = 0; i < 4; ++i) dma16(src + i * 256 + lane * 4, dl + i * 256);
    }
    asm volatile("s_waitcnt vmcnt(0)" ::: "memory");
    __builtin_amdgcn_s_barrier();

    unsigned bcnt = 0;
    int cur = 0;
    for (int s = 0; s <= 64; ++s) {
        const bool act = L1 ? (s < 64) : (s > 0);
        const int t = L1 ? s : s - 1;
        float* x = L1 ? (A.XT + (size_t)(act ? t : 0) * 32768)
                      : (x2v + (size_t)((act ? t : 0) & 1) * 32768);

        for (int ph = 0; ph < 5; ++ph) {
            // issue next mog-phase weight DMA into the other buffer
            {
                const float* src = mW + (size_t)((ph + 1) % 5) * 1048576
                                      + (size_t)j0 * 1024 + wv * 1024;
                float* dl = &wbuf[cur ^ 1][wv * 1024];
#pragma unroll
                for (int i = 0; i < 4; ++i) dma16(src + i * 256 + lane * 4, dl + i * 256);
            }
            if (act) {
                const float *gin, *srcv; float* dstv;
                switch (ph) {
                    default:
                    case 0: gin = h;  srcv = x;  dstv = x;  break;
                    case 1: gin = x;  srcv = h;  dstv = hm; break;
                    case 2: gin = hm; srcv = x;  dstv = x;  break;
                    case 3: gin = x;  srcv = hm; dstv = hm; break;
                    case 4: gin = hm; srcv = x;  dstv = x;  break;
                }
                const float* gp = gin + kq * 4096 + b * 4;
                const float* wl = &wbuf[cur][kq * 128];
                float a0 = 0.f, a1 = 0.f, a2 = 0.f, a3 = 0.f;
#pragma unroll 8
                for (int c2 = 0; c2 < 32; ++c2) {
                    float2 p01 = ldc8(gp + c2 * 128);
                    float2 p23 = ldc8(gp + c2 * 128 + 2);
                    float4 w = *(const float4*)(wl + c2 * 4);
                    a0 += p01.x * w.x + p01.y * w.y + p23.x * w.z + p23.y * w.w;
                    w = *(const float4*)(wl + 1024 + c2 * 4);
                    a1 += p01.x * w.x + p01.y * w.y + p23.x * w.z + p23.y * w.w;
                    w = *(const float4*)(wl + 2048 + c2 * 4);
                    a2 += p01.x * w.x + p01.y * w.y + p23.x * w.z + p23.y * w.w;
                    w = *(const float4*)(wl + 3072 + c2 * 4);
                    a3 += p01.x * w.x + p01.y * w.y + p23.x * w.z + p23.y * w.w;
                }
                a0 += __shfl_xor(a0, 32);
                a1 += __shfl_xor(a1, 32);
                a2 += __shfl_xor(a2, 32);
                a3 += __shfl_xor(a3, 32);
                if ((tid & 32) == 0) {
                    red2[wv][0][b] = a0; red2[wv][1][b] = a1;
                    red2[wv][2][b] = a2; red2[wv][3][b] = a3;
                }
                __syncthreads();
                if (tid < 128) {
                    int j = tid >> 5, bb = tid & 31;
                    float ssum = (red2[0][j][bb] + red2[1][j][bb])
                               + (red2[2][j][bb] + red2[3][j][bb]);
                    int ja = j0 + j;
                    ssum += mb[ph * 1024 + ja];
                    float gmul = 2.0f * sigmoidf_(ssum);
                    int idx = ((ja >> 2) * 32 + bb) * 4 + (ja & 3);
                    stc4(&dstv[idx], gmul * ldc4(&srcv[idx]));
                }
            }
            gbar(A.bar, ++bcnt);
            cur ^= 1;
        }

        // ---------------- LSTM slot: stream 8x16KB weight chunks through LDS ----------------
        {
            float* P = &wbuf[cur ^ 1][0];
            float* Q = &lext[0];
            if (act) {
                {
                    const float* WS = Wih;
#pragma unroll
                    for (int i = 0; i < 4; ++i) {
                        int rr = wv * 4 + i;
                        int R = (rr >> 2) * 1024 + j0 + (rr & 3);
                        dma16(WS + (size_t)R * 1024 + lane * 4, Q + rr * 256);
                    }
                }
                asm volatile("s_waitcnt vmcnt(0)" ::: "memory");
                __builtin_amdgcn_s_barrier();

                float acc[16];
#pragma unroll
                for (int i = 0; i < 16; ++i) acc[i] = 0.f;

                for (int c = 0; c < 8; ++c) {
                    float* bc = (c & 1) ? P : Q;
                    const int side = c >> 2, kseg = c & 3;
                    const float* ab = (side ? hm : x) + (size_t)(kseg * 64 + kq * 8) * 128 + b * 4;
                    float2 av2[16];
#pragma unroll
                    for (int i = 0; i < 8; ++i) {
                        av2[2 * i]     = ldc8(ab + i * 128);
                        av2[2 * i + 1] = ldc8(ab + i * 128 + 2);
                    }
                    __builtin_amdgcn_sched_barrier(0);
                    if (c < 7) {
                        const int cn = c + 1;
                        const int nside = cn >> 2, nkseg = cn & 3;
                        const float* WS = nside ? Whh : Wih;
                        float* nb2 = (c & 1) ? Q : P;
#pragma unroll
                        for (int i = 0; i < 4; ++i) {
                            int rr = wv * 4 + i;
                            int R = (rr >> 2) * 1024 + j0 + (rr & 3);
                            dma16(WS + (size_t)R * 1024 + nkseg * 256 + lane * 4, nb2 + rr * 256);
                        }
                    }
                    __builtin_amdgcn_sched_barrier(0);
#pragma unroll
                    for (int i = 0; i < 8; ++i) {
#pragma unroll
                        for (int rr = 0; rr < 16; ++rr) {
                            float4 w = *(const float4*)(bc + rr * 256 + kq * 32 + i * 4);
                            acc[rr] += av2[2 * i].x * w.x + av2[2 * i].y * w.y
                                     + av2[2 * i + 1].x * w.z + av2[2 * i + 1].y * w.w;
                        }
                    }
                    asm volatile("s_waitcnt vmcnt(0) lgkmcnt(0)" ::: "memory");
                    __builtin_amdgcn_s_barrier();
                }

#pragma unroll
                for (int i = 0; i < 16; ++i) acc[i] += __shfl_xor(acc[i], 32);
                if ((tid & 32) == 0) {
#pragma unroll
                    for (int i = 0; i < 16; ++i) red2[wv][i][b] = acc[i];
                }
                __syncthreads();
                if (tid < 128) {
                    int jj = tid >> 5, bb = tid & 31;
                    int ja = j0 + jj;
                    float gi = 0.f, gf = 0.f, gg = 0.f, go = 0.f;
#pragma unroll
                    for (int w = 0; w < 4; ++w) {
                        gi += red2[w][0 + jj][bb];
                        gf += red2[w][4 + jj][bb];
                        gg += red2[w][8 + jj][bb];
                        go += red2[w][12 + jj][bb];
                    }
                    gi += bih[ja] + bhh[ja];
                    gf += bih[1024 + ja] + bhh[1024 + ja];
                    gg += bih[2048 + ja] + bhh[2048 + ja];
                    go += bih[3072 + ja] + bhh[3072 + ja];
                    int idx = ((ja >> 2) * 32 + bb) * 4 + (ja & 3);
                    float cn = sigmoidf_(gf) * cc[idx] + sigmoidf_(gi) * tanhf_(gg);
                    cc[idx] = cn;                      // block-local, cached
                    float hn = sigmoidf_(go) * tanhf_(cn);
                    stc4(&h[idx], hn);                 // cross-block: coherent
                    if (L1) {
                        stc4(&x2v[(size_t)(t & 1) * 32768 + idx], hn);
                    } else {
                        A.hs[(size_t)bb * 65536 + (size_t)t * 1024 + ja] = hn;  // read after kernel end
                    }
                }
            }
            gbar(A.bar, ++bcnt);
        }
    }
}

// ---------------- embedding gather into k4-interleaved layout ----------------
__global__ __launch_bounds__(256) void gather_embed(const int* __restrict__ seq,
                                                    const float* __restrict__ emb,
                                                    float* __restrict__ XT) {
    int t = blockIdx.x;
    const float4* emb4 = (const float4*)emb;
    float4* xt4 = (float4*)(XT + (size_t)t * 32768);
#pragma unroll 4
    for (int b = 0; b < 32; ++b) {
        int row = seq[b * 64 + t];
        float4 v = emb4[(size_t)row * 256 + threadIdx.x];
        xt4[threadIdx.x * 32 + b] = v;
    }
}

// ---------------- fp32 -> bf16 ----------------
__global__ __launch_bounds__(256) void f32_to_bf16(const float* __restrict__ in,
                                                   unsigned short* __restrict__ out, int n) {
    int i = (blockIdx.x * 256 + threadIdx.x) * 8;
    if (i + 7 < n) {
        float4 f0 = *(const float4*)(in + i);
        float4 f1 = *(const float4*)(in + i + 4);
        bf16x8 v;
        v[0] = (short)f2bf(f0.x); v[1] = (short)f2bf(f0.y);
        v[2] = (short)f2bf(f0.z); v[3] = (short)f2bf(f0.w);
        v[4] = (short)f2bf(f1.x); v[5] = (short)f2bf(f1.y);
        v[6] = (short)f2bf(f1.z); v[7] = (short)f2bf(f1.w);
        *(bf16x8*)(out + i) = v;
    }
}

// ---------------- output projection (bf16 MFMA, 128x128 tile) ----------------
__global__ __launch_bounds__(256) void out_proj(const unsigned short* __restrict__ hsb,
                                                const float* __restrict__ emb,
                                                const float* __restrict__ fcb,
                                                float* __restrict__ out) {
    __shared__ unsigned short Al[128 * 40];
    __shared__ unsigned short Bl[128 * 40];
    int tid = threadIdx.x;
    int n0 = blockIdx.x * 128;
    int m0 = blockIdx.y * 128;
    int wid = tid >> 6, l = tid & 63;
    int wm = wid >> 1, wn = wid & 1;
    int c16 = l & 15, kg = l >> 4;

    f32x4 acc[4][4];
#pragma unroll
    for (int i = 0; i < 4; i++)
#pragma unroll
        for (int j = 0; j < 4; j++) acc[i][j] = (f32x4){0.f, 0.f, 0.f, 0.f};

    for (int k0 = 0; k0 < 1024; k0 += 32) {
#pragma unroll
        for (int i = 0; i < 2; i++) {
            int id = i * 256 + tid;
            int r = id >> 2, ccc = id & 3;
            *(bf16x8*)&Al[r * 40 + ccc * 8] =
                *(const bf16x8*)(hsb + (size_t)(m0 + r) * 1024 + k0 + ccc * 8);
        }
#pragma unroll
        for (int i = 0; i < 2; i++) {
            int id = i * 256 + tid;
            int r = id >> 2, ccc = id & 3;
            const float* src = emb + (size_t)(n0 + r) * 1024 + k0 + ccc * 8;
            float4 f0 = *(const float4*)(src);
            float4 f1 = *(const float4*)(src + 4);
            bf16x8 v;
            v[0] = (short)f2bf(f0.x); v[1] = (short)f2bf(f0.y);
            v[2] = (short)f2bf(f0.z); v[3] = (short)f2bf(f0.w);
            v[4] = (short)f2bf(f1.x); v[5] = (short)f2bf(f1.y);
            v[6] = (short)f2bf(f1.z); v[7] = (short)f2bf(f1.w);
            *(bf16x8*)&Bl[r * 40 + ccc * 8] = v;
        }
        __syncthreads();

        bf16x8 afr[4], bfr[4];
#pragma unroll
        for (int i = 0; i < 4; i++)
            afr[i] = *(const bf16x8*)&Al[(wm * 64 + i * 16 + c16) * 40 + kg * 8];
#pragma unroll
        for (int j = 0; j < 4; j++)
            bfr[j] = *(const bf16x8*)&Bl[(wn * 64 + j * 16 + c16) * 40 + kg * 8];
#pragma unroll
        for (int i = 0; i < 4; i++)
#pragma unroll
            for (int j = 0; j < 4; j++)
                acc[i][j] = __builtin_amdgcn_mfma_f32_16x16x32_bf16(afr[i], bfr[j], acc[i][j], 0, 0, 0);
        __syncthreads();
    }

#pragma unroll
    for (int i = 0; i < 4; i++) {
        int row = m0 + wm * 64 + i * 16 + kg * 4;
#pragma unroll
        for (int j = 0; j < 4; j++) {
            int col = n0 + wn * 64 + j * 16 + c16;
            float fb = fcb[col];
#pragma unroll
            for (int r = 0; r < 4; r++)
                out[(size_t)(row + r) * 32000 + col] = acc[i][j][r] + fb;
        }
    }
}

// ---------------- host ----------------
extern "C" void kernel_launch(void* const* d_in, const int* in_sizes, int n_in,
                              void* d_out, int out_size, void* d_ws, size_t ws_size,
                              hipStream_t stream) {
    const int*   seq    = (const int*)d_in[0];
    const float* emb    = (const float*)d_in[2];
    const float* mog1_W = (const float*)d_in[3];
    const float* mog1_b = (const float*)d_in[4];
    const float* W_ih1  = (const float*)d_in[5];
    const float* W_hh1  = (const float*)d_in[6];
    const float* b_ih1  = (const float*)d_in[7];
    const float* b_hh1  = (const float*)d_in[8];
    const float* mog2_W = (const float*)d_in[9];
    const float* mog2_b = (const float*)d_in[10];
    const float* W_ih2  = (const float*)d_in[11];
    const float* W_hh2  = (const float*)d_in[12];
    const float* b_ih2  = (const float*)d_in[13];
    const float* b_hh2  = (const float*)d_in[14];
    const float* fc_b   = (const float*)d_in[15];

    char* ws = (char*)d_ws;
    float* XT = (float*)ws;                                  // 8 MB
    float* st = (float*)(ws + 8388608);                      // 1 MB
    unsigned* bar = (unsigned*)(ws + 9437184);               // 16 KB (64 padded counters + gen)
    unsigned short* hsb = (unsigned short*)(ws + 9453568);   // 4 MB

    float* out0 = (float*)d_out;
    float* hs   = out0 + 65536000LL;

    hipMemsetAsync(st, 0, 524288, stream);
    hipMemsetAsync(bar, 0, 16384, stream);

    gather_embed<<<64, 256, 0, stream>>>(seq, emb, XT);

    RArgs a;
    a.m1W = mog1_W; a.m1b = mog1_b;
    a.Wih1 = W_ih1; a.Whh1 = W_hh1; a.bih1 = b_ih1; a.bhh1 = b_hh1;
    a.m2W = mog2_W; a.m2b = mog2_b;
    a.Wih2 = W_ih2; a.Whh2 = W_hh2; a.bih2 = b_ih2; a.bhh2 = b_hh2;
    a.XT = XT; a.st = st; a.hs = hs; a.bar = bar;

    reck<<<512, 256, 0, stream>>>(a);

    f32_to_bf16<<<1024, 256, 0, stream>>>(hs, hsb, 2097152);
    out_proj<<<dim3(250, 16), 256, 0, stream>>>(hsb, emb, fc_b, out0);
}